// Round 4
// baseline (171.796 us; speedup 1.0000x reference)
//
#include <hip/hip_runtime.h>
#include <math.h>

#define T_DIM 64
#define C_DIM 256
#define H_DIM 56
#define W_DIM 56
#define HW    (H_DIM * W_DIM)        // 3136
#define HW4   (HW / 4)               // 784
#define CHW   (C_DIM * HW)
#define THW   (T_DIM * HW)           // 200704

// ---------------------------------------------------------------------------
// Gate kernel: register-blocked conv, block = 4 waves = 4 channel-groups of
// the SAME (side, t, hh) tile; LDS block-reduce -> 8 partial planes.
// blockIdx.x = ((side*4+gq)*2+hh)*64 + t  (1024 blocks)
// Lane (rg = lane>>4, wg = lane&15, active wg<14): rows r0..r0+6, cols w0..w0+3.
// Halo columns come from neighbor lanes via __shfl (no scalar edge loads).
// ---------------------------------------------------------------------------
__global__ __launch_bounds__(256) void gate_kernel(
    const float* __restrict__ x,
    const float* __restrict__ w_l,
    const float* __restrict__ w_r,
    float* __restrict__ pbuf)
{
    __shared__ float4 red[4][7][64];   // 28672 B

    const int b    = blockIdx.x;
    const int t    = b & 63;
    const int hh   = (b >> 6) & 1;
    const int gq   = (b >> 7) & 3;
    const int side = (b >> 9);

    const int waveid = __builtin_amdgcn_readfirstlane((int)(threadIdx.x >> 6));
    const int lane = threadIdx.x & 63;
    const int wg   = lane & 15;
    const int rg   = lane >> 4;
    const bool act = (wg < 14);
    const int w0   = act ? wg * 4 : 52;
    const int r0   = hh * 28 + rg * 7;
    const bool have_l = (wg > 0);
    const bool have_r = (wg < 13);

    const int c0 = side * 64 + gq * 16 + waveid * 4;
    const float* wtab = (side ? w_r : w_l) + (gq * 16 + waveid * 4) * 27;

    const int tm = (t + 63) & 63, tp = (t + 1) & 63;
    const float* tbase[3] = { x + (size_t)tm * CHW,
                              x + (size_t)t  * CHW,
                              x + (size_t)tp * CHW };

    float acc[7][4];
    #pragma unroll
    for (int j = 0; j < 7; ++j)
        #pragma unroll
        for (int k = 0; k < 4; ++k) acc[j][k] = 0.f;

    for (int ci = 0; ci < 4; ++ci) {
        float wgt[27];
        #pragma unroll
        for (int k = 0; k < 27; ++k) wgt[k] = wtab[ci * 27 + k];

        #pragma unroll
        for (int dt = 0; dt < 3; ++dt) {
            const float* plane = tbase[dt] + (size_t)(c0 + ci) * HW;

            #pragma unroll
            for (int s9 = 0; s9 < 9; ++s9) {
                const int sr = r0 - 1 + s9;
                bool rv = true;
                int  srow = sr;
                if (s9 == 0)      { rv = (sr >= 0);     srow = rv ? sr : 0; }
                else if (s9 == 8) { rv = (sr < H_DIM);  srow = rv ? sr : (H_DIM - 1); }

                const float* row = plane + srow * W_DIM;
                float4 m  = *(const float4*)(row + w0);
                float  fl = __shfl_up(m.w, 1);    // lane-1's row[w0+3] == row[w0-1]
                float  fr = __shfl_down(m.x, 1);  // lane+1's row[w0]   == row[w0+4]

                float f[6];
                f[0] = have_l ? fl : 0.f;
                f[1] = m.x; f[2] = m.y; f[3] = m.z; f[4] = m.w;
                f[5] = have_r ? fr : 0.f;
                if ((s9 == 0 || s9 == 8) && !rv) {
                    f[0] = 0.f; f[1] = 0.f; f[2] = 0.f;
                    f[3] = 0.f; f[4] = 0.f; f[5] = 0.f;
                }

                const int jlo = (s9 >= 2) ? s9 - 2 : 0;
                const int jhi = (s9 <= 6) ? s9 : 6;
                #pragma unroll
                for (int j = jlo; j <= jhi; ++j) {
                    const int dh = s9 - j;
                    const float w0t = wgt[dt * 9 + dh * 3 + 0];
                    const float w1t = wgt[dt * 9 + dh * 3 + 1];
                    const float w2t = wgt[dt * 9 + dh * 3 + 2];
                    #pragma unroll
                    for (int k = 0; k < 4; ++k)
                        acc[j][k] += w0t * f[k] + w1t * f[k + 1] + w2t * f[k + 2];
                }
            }
        }
    }

    #pragma unroll
    for (int j = 0; j < 7; ++j) {
        float4 v; v.x = acc[j][0]; v.y = acc[j][1]; v.z = acc[j][2]; v.w = acc[j][3];
        red[waveid][j][lane] = v;
    }
    __syncthreads();

    if (waveid == 0 && act) {
        float* pp = pbuf + (size_t)(side * 4 + gq) * THW
                         + (size_t)t * HW + r0 * W_DIM + w0;
        #pragma unroll
        for (int j = 0; j < 7; ++j) {
            float4 a = red[0][j][lane], b2 = red[1][j][lane];
            float4 c = red[2][j][lane], d  = red[3][j][lane];
            float4 v;
            v.x = (a.x + b2.x) + (c.x + d.x);
            v.y = (a.y + b2.y) + (c.y + d.y);
            v.z = (a.z + b2.z) + (c.z + d.z);
            v.w = (a.w + b2.w) + (c.w + d.w);
            *(float4*)(pp + j * W_DIM) = v;
        }
    }
}

// ---------------------------------------------------------------------------
// Reduce 4 partials per side + bias + tanh -> gbuf (gl at 0, gr at THW).
// ---------------------------------------------------------------------------
__global__ __launch_bounds__(256) void reduce_tanh_kernel(
    const float* __restrict__ pbuf,
    float* __restrict__ gbuf,
    const float* __restrict__ b_l,
    const float* __restrict__ b_r)
{
    const int i = blockIdx.x * 256 + threadIdx.x;   // over THW/4 = 50176
    const float4* p4 = (const float4*)pbuf;
    float4* g4 = (float4*)gbuf;

    float4 a = {0.f,0.f,0.f,0.f}, b = {0.f,0.f,0.f,0.f};
    #pragma unroll
    for (int g = 0; g < 4; ++g) {
        float4 va = p4[(size_t)g       * (THW/4) + i];
        float4 vb = p4[(size_t)(4 + g) * (THW/4) + i];
        a.x += va.x; a.y += va.y; a.z += va.z; a.w += va.w;
        b.x += vb.x; b.y += vb.y; b.z += vb.z; b.w += vb.w;
    }
    const float bl = b_l[0], br = b_r[0];
    float4 gl, gr;
    gl.x = tanhf(a.x + bl); gl.y = tanhf(a.y + bl);
    gl.z = tanhf(a.z + bl); gl.w = tanhf(a.w + bl);
    gr.x = tanhf(b.x + br); gr.y = tanhf(b.y + br);
    gr.z = tanhf(b.z + br); gr.w = tanhf(b.w + br);
    g4[i]             = gl;
    g4[(THW/4) + i]   = gr;
}

// ---------------------------------------------------------------------------
// Combine: thread owns (c, h, w4) and iterates 16 t's, carrying x/g in regs
// so x is read exactly once. Branches are block-uniform (64*784 = 196*256).
// blockIdx.x over 784 (c,h,w4 flat / 256), blockIdx.y = t-chunk (0..3).
// ---------------------------------------------------------------------------
__global__ __launch_bounds__(256) void combine_kernel(
    const float* __restrict__ x,
    const float* __restrict__ g,
    float* __restrict__ out)
{
    const int tid = blockIdx.x * 256 + threadIdx.x;   // (c*784 + h*14 + w4)
    const int t0  = blockIdx.y * 16;
    const int c   = tid / HW4;
    const int gb  = tid - c * HW4;                    // h*14 + w4

    const float4* x4 = (const float4*)x;
    float4*       o4 = (float4*)out;
    const size_t  ts = C_DIM * HW4;                   // t-plane stride in float4
    const size_t  base = tid;

    if (c >= 128) {
        #pragma unroll 4
        for (int i = 0; i < 16; ++i) {
            const size_t idx = (size_t)(t0 + i) * ts + base;
            o4[idx] = x4[idx];
        }
    } else if (c < 64) {
        const float4* gl4 = (const float4*)g;
        float4 xv = x4[(size_t)t0 * ts + base];
        float4 g0 = gl4[t0 * HW4 + gb];
        #pragma unroll 4
        for (int i = 0; i < 16; ++i) {
            const int t  = t0 + i;
            const int tp = (t + 1) & 63;
            float4 xn = x4[(size_t)tp * ts + base];
            float4 g1 = gl4[tp * HW4 + gb];
            float4 r;
            r.x = xv.x - g0.x * xv.x + g1.x * xn.x;
            r.y = xv.y - g0.y * xv.y + g1.y * xn.y;
            r.z = xv.z - g0.z * xv.z + g1.z * xn.z;
            r.w = xv.w - g0.w * xv.w + g1.w * xn.w;
            o4[(size_t)t * ts + base] = r;
            xv = xn; g0 = g1;
        }
    } else {
        const float4* gr4 = (const float4*)(g + THW);
        const int tmi = (t0 + 63) & 63;
        float4 xm = x4[(size_t)tmi * ts + base];
        float4 gm = gr4[tmi * HW4 + gb];
        #pragma unroll 4
        for (int i = 0; i < 16; ++i) {
            const int t = t0 + i;
            float4 xv = x4[(size_t)t * ts + base];
            float4 g0 = gr4[t * HW4 + gb];
            float4 r;
            r.x = xv.x - g0.x * xv.x + gm.x * xm.x;
            r.y = xv.y - g0.y * xv.y + gm.y * xm.y;
            r.z = xv.z - g0.z * xv.z + gm.z * xm.z;
            r.w = xv.w - g0.w * xv.w + gm.w * xm.w;
            o4[(size_t)t * ts + base] = r;
            xm = xv; gm = g0;
        }
    }
}

extern "C" void kernel_launch(void* const* d_in, const int* in_sizes, int n_in,
                              void* d_out, int out_size, void* d_ws, size_t ws_size,
                              hipStream_t stream) {
    const float* x   = (const float*)d_in[0];
    const float* w_l = (const float*)d_in[1];
    const float* b_l = (const float*)d_in[2];
    const float* w_r = (const float*)d_in[3];
    const float* b_r = (const float*)d_in[4];
    float* out  = (float*)d_out;
    float* pbuf = (float*)d_ws;                    // 8 partial planes
    float* gbuf = pbuf + (size_t)8 * THW;          // 2 gate planes

    gate_kernel<<<1024, 256, 0, stream>>>(x, w_l, w_r, pbuf);
    reduce_tanh_kernel<<<THW / 4 / 256, 256, 0, stream>>>(pbuf, gbuf, b_l, b_r);
    combine_kernel<<<dim3(HW4 * C_DIM / 256, 4), 256, 0, stream>>>(x, gbuf, out);
}